// Round 13
// baseline (587.641 us; speedup 1.0000x reference)
//
#include <hip/hip_runtime.h>

typedef unsigned short u16;
typedef __attribute__((ext_vector_type(8))) short bf8;   // 8 bf16 in 4 VGPRs
typedef __attribute__((ext_vector_type(4))) float f32x4;

#define DEVINL __device__ __forceinline__

constexpr int NN = 4096, DD = 256, EE = 131072, HHD = 8, HIDN = 512, COEF_ = 7;

DEVINL u16 f2bf(float f) {
  union { float f; unsigned int i; } c; c.f = f;
  unsigned int u = c.i;
  return (u16)((u + 0x7FFFu + ((u >> 16) & 1u)) >> 16);
}
DEVINL unsigned pk2(float a, float b) {
  return (unsigned)f2bf(a) | ((unsigned)f2bf(b) << 16);
}
DEVINL float siluf(float x) { return x / (1.f + __expf(-x)); }

// ---------------- GCN graph part: CSR build + gather (no data atomics) ----------------

__global__ void degcnt_k(const int* __restrict__ ei, float* __restrict__ deg,
                         int* __restrict__ cnt) {
  int e = blockIdx.x * 256 + threadIdx.x;
  if (e < EE) {
    atomicAdd(&deg[ei[e]], 1.0f);
    atomicAdd(&cnt[ei[EE + e]], 1);
  }
}

__global__ void dis_k(float* __restrict__ deg) {
  int i = blockIdx.x * 256 + threadIdx.x;
  if (i < NN) deg[i] = rsqrtf(deg[i] + 1.0f);  // +1 self loop
}

__global__ __launch_bounds__(1024) void scan_k(const int* __restrict__ cnt,
    int* __restrict__ rowptr, int* __restrict__ cursor) {
  __shared__ int sm[1024];
  int t = threadIdx.x;
  int4 c = ((const int4*)cnt)[t];
  int tot = c.x + c.y + c.z + c.w;
  sm[t] = tot;
  __syncthreads();
  for (int off = 1; off < 1024; off <<= 1) {
    int v = (t >= off) ? sm[t - off] : 0;
    __syncthreads();
    sm[t] += v;
    __syncthreads();
  }
  int excl = sm[t] - tot;
  int4 r;
  r.x = excl; r.y = excl + c.x; r.z = r.y + c.y; r.w = r.z + c.z;
  ((int4*)rowptr)[t] = r;
  ((int4*)cursor)[t] = r;
  if (t == 1023) rowptr[4096] = excl + tot;
}

__global__ void fill_k(const int* __restrict__ ei, const float* __restrict__ dis,
    int* __restrict__ cursor, int* __restrict__ esrc, float* __restrict__ ew) {
  int e = blockIdx.x * 256 + threadIdx.x;
  if (e < EE) {
    int s = ei[e], t = ei[EE + e];
    int pos = atomicAdd(&cursor[t], 1);
    esrc[pos] = s;
    ew[pos] = dis[s];
  }
}

__global__ __launch_bounds__(256) void gather_k(const float* __restrict__ x,
    const float* __restrict__ dis, const int* __restrict__ rowptr,
    const int* __restrict__ esrc, const float* __restrict__ ew,
    float* __restrict__ aggr) {
  int node = blockIdx.x * 4 + (threadIdx.x >> 6);
  int lane = threadIdx.x & 63;
  int d0 = lane * 4;
  float dn = dis[node];
  const float4 xv = *(const float4*)(x + (size_t)node * DD + d0);
  float4 acc;
  acc.x = dn * xv.x; acc.y = dn * xv.y; acc.z = dn * xv.z; acc.w = dn * xv.w;
  int beg = rowptr[node], end = rowptr[node + 1];
  for (int base = beg; base < end; base += 64) {
    int idx = base + lane;
    int sv = (idx < end) ? esrc[idx] : 0;
    float wv = (idx < end) ? ew[idx] : 0.f;
    int chunk = min(64, end - base);
    int j = 0;
    for (; j + 2 <= chunk; j += 2) {
      int s0 = __shfl(sv, j), s1 = __shfl(sv, j + 1);
      float w0 = __shfl(wv, j), w1 = __shfl(wv, j + 1);
      const float4 v0 = *(const float4*)(x + (size_t)s0 * DD + d0);
      const float4 v1 = *(const float4*)(x + (size_t)s1 * DD + d0);
      acc.x = fmaf(w0, v0.x, acc.x); acc.y = fmaf(w0, v0.y, acc.y);
      acc.z = fmaf(w0, v0.z, acc.z); acc.w = fmaf(w0, v0.w, acc.w);
      acc.x = fmaf(w1, v1.x, acc.x); acc.y = fmaf(w1, v1.y, acc.y);
      acc.z = fmaf(w1, v1.z, acc.z); acc.w = fmaf(w1, v1.w, acc.w);
    }
    if (j < chunk) {
      int s0 = __shfl(sv, j);
      float w0 = __shfl(wv, j);
      const float4 v0 = *(const float4*)(x + (size_t)s0 * DD + d0);
      acc.x = fmaf(w0, v0.x, acc.x); acc.y = fmaf(w0, v0.y, acc.y);
      acc.z = fmaf(w0, v0.z, acc.z); acc.w = fmaf(w0, v0.w, acc.w);
    }
  }
  float4 outv;
  outv.x = dn * acc.x; outv.y = dn * acc.y; outv.z = dn * acc.z; outv.w = dn * acc.w;
  *(float4*)(aggr + (size_t)node * DD + d0) = outv;
}

// ---------------- bf16 MFMA GEMM, 64x64 tile, BK=128, LDS double-buffer ----------------
// C[n,m] = A[n,k] @ W[m,k]^T. EP: 0=bias 1=bias+silu 2=(acc+bias)*bn+res(+extra) 3=qkv-bf16+Vt
// W_KAN: k>=256 region = spl[m][1792]*scl[m][256] (idx/7), k<256 = Wb[m][256].
// k must be a multiple of 128 (uses: 256, 512, 2048). ONE barrier per 128-K step.

#define LSW(r, kb) ((((r) * 128 + ((kb) ^ (((r) & 7) << 4)))) >> 1)

template<int EP, bool A_BF16, bool W_KAN>
__global__ __launch_bounds__(256) void mgemm(
    const void* __restrict__ Aptr, const float* __restrict__ Wb,
    const float* __restrict__ Wspl, const float* __restrict__ Wscl,
    const float* __restrict__ bias, const float* __restrict__ gam,
    const float* __restrict__ bet, const float* __restrict__ xres,
    const float* __restrict__ extra, float* __restrict__ C,
    u16* __restrict__ q16, u16* __restrict__ Vt, int n, int m, int k)
{
  __shared__ u16 Al[2][2][64 * 64];   // [dbuf][k-subtile] 32 KB
  __shared__ u16 Wl[2][2][64 * 64];   // 32 KB
  const int tid = threadIdx.x;
  const int wid = tid >> 6, lane = tid & 63;
  const int l15 = lane & 15, hi16 = lane >> 4;
  const int wr = wid >> 1, wc = wid & 1;
  const int bn = blockIdx.x * 64, bm = blockIdx.y * 64;
  const int sr = tid >> 2, sc0 = (tid & 3) * 16;

  float rAf[2][16];
  uint4 rAb[2][2];
  float rW[2][16];

#define MG_LOADA(S, KT) do {                                                    \
    if (A_BF16) {                                                               \
      const u16* Ap = (const u16*)Aptr + (size_t)(bn + sr) * k + (KT) + sc0;    \
      rAb[S][0] = *(const uint4*)Ap;                                            \
      rAb[S][1] = *(const uint4*)(Ap + 8);                                      \
    } else {                                                                    \
      const float* Ap = (const float*)Aptr + (size_t)(bn + sr) * k + (KT) + sc0;\
      _Pragma("unroll")                                                         \
      for (int c = 0; c < 4; ++c)                                               \
        *(float4*)&rAf[S][c * 4] = *(const float4*)(Ap + c * 4);                \
    }                                                                           \
  } while (0)

#define MG_LOADW(S, KT) do {                                                    \
    if (W_KAN && (KT) >= 256) {                                                 \
      int base = (KT) - 256 + sc0;                                              \
      const float* sp = Wspl + (size_t)(bm + sr) * 1792 + base;                 \
      const float* sl = Wscl + (size_t)(bm + sr) * 256;                         \
      _Pragma("unroll")                                                         \
      for (int j = 0; j < 16; ++j) {                                            \
        unsigned idx = (unsigned)(base + j);                                    \
        rW[S][j] = sp[j] * sl[(idx * 9363u) >> 16];                             \
      }                                                                         \
    } else {                                                                    \
      const float* Wp = Wb + (size_t)(bm + sr) * (W_KAN ? 256 : k) + (KT) + sc0;\
      _Pragma("unroll")                                                         \
      for (int c = 0; c < 4; ++c)                                               \
        *(float4*)&rW[S][c * 4] = *(const float4*)(Wp + c * 4);                 \
    }                                                                           \
  } while (0)

#define MG_WRITE(B, S) do {                                                     \
    if (A_BF16) {                                                               \
      *(uint4*)&Al[B][S][LSW(sr, 2 * sc0)] = rAb[S][0];                         \
      *(uint4*)&Al[B][S][LSW(sr, 2 * sc0 + 16)] = rAb[S][1];                    \
    } else {                                                                    \
      uint4 w;                                                                  \
      w.x = pk2(rAf[S][0], rAf[S][1]);  w.y = pk2(rAf[S][2], rAf[S][3]);        \
      w.z = pk2(rAf[S][4], rAf[S][5]);  w.w = pk2(rAf[S][6], rAf[S][7]);        \
      *(uint4*)&Al[B][S][LSW(sr, 2 * sc0)] = w;                                 \
      w.x = pk2(rAf[S][8], rAf[S][9]);  w.y = pk2(rAf[S][10], rAf[S][11]);      \
      w.z = pk2(rAf[S][12], rAf[S][13]); w.w = pk2(rAf[S][14], rAf[S][15]);     \
      *(uint4*)&Al[B][S][LSW(sr, 2 * sc0 + 16)] = w;                            \
    }                                                                           \
    uint4 w;                                                                    \
    w.x = pk2(rW[S][0], rW[S][1]);  w.y = pk2(rW[S][2], rW[S][3]);              \
    w.z = pk2(rW[S][4], rW[S][5]);  w.w = pk2(rW[S][6], rW[S][7]);              \
    *(uint4*)&Wl[B][S][LSW(sr, 2 * sc0)] = w;                                   \
    w.x = pk2(rW[S][8], rW[S][9]);  w.y = pk2(rW[S][10], rW[S][11]);            \
    w.z = pk2(rW[S][12], rW[S][13]); w.w = pk2(rW[S][14], rW[S][15]);           \
    *(uint4*)&Wl[B][S][LSW(sr, 2 * sc0 + 16)] = w;                              \
  } while (0)

#define MG_MFMA(B, S) do {                                                      \
    _Pragma("unroll")                                                           \
    for (int kk = 0; kk < 64; kk += 32) {                                       \
      const int kb = (kk + hi16 * 8) * 2;                                       \
      bf8 av[2], bv[2];                                                         \
      av[0] = *(const bf8*)&Al[B][S][LSW(wr * 32 + l15, kb)];                   \
      av[1] = *(const bf8*)&Al[B][S][LSW(wr * 32 + 16 + l15, kb)];              \
      bv[0] = *(const bf8*)&Wl[B][S][LSW(wc * 32 + l15, kb)];                   \
      bv[1] = *(const bf8*)&Wl[B][S][LSW(wc * 32 + 16 + l15, kb)];              \
      acc[0][0] = __builtin_amdgcn_mfma_f32_16x16x32_bf16(av[0], bv[0], acc[0][0], 0, 0, 0); \
      acc[0][1] = __builtin_amdgcn_mfma_f32_16x16x32_bf16(av[0], bv[1], acc[0][1], 0, 0, 0); \
      acc[1][0] = __builtin_amdgcn_mfma_f32_16x16x32_bf16(av[1], bv[0], acc[1][0], 0, 0, 0); \
      acc[1][1] = __builtin_amdgcn_mfma_f32_16x16x32_bf16(av[1], bv[1], acc[1][1], 0, 0, 0); \
    }                                                                           \
  } while (0)

  f32x4 acc[2][2] = {};
  MG_LOADA(0, 0); MG_LOADW(0, 0);
  MG_LOADA(1, 64); MG_LOADW(1, 64);
  MG_WRITE(0, 0); MG_WRITE(0, 1);
  __syncthreads();
  int cur = 0;
  for (int kt = 0; kt < k; kt += 128) {
    const bool more = kt + 128 < k;
    if (more) {
      MG_LOADA(0, kt + 128); MG_LOADW(0, kt + 128);
      MG_LOADA(1, kt + 192); MG_LOADW(1, kt + 192);
    }
    MG_MFMA(cur, 0); MG_MFMA(cur, 1);          // 16 MFMA cover the loads
    if (more) { MG_WRITE(cur ^ 1, 0); MG_WRITE(cur ^ 1, 1); }
    __syncthreads();                            // single barrier per K-step
    cur ^= 1;
  }
  // epilogue: C/D col = lane&15, row = (lane>>4)*4 + j
#pragma unroll
  for (int fr = 0; fr < 2; ++fr)
#pragma unroll
    for (int fc = 0; fc < 2; ++fc) {
      int col = bm + wc * 32 + fc * 16 + l15;
      float bb = bias ? bias[col] : 0.f;
      float gs = 0.f, bt = 0.f;
      if (EP == 2) {
        gs = gam[col] * rsqrtf(1.f + 1e-5f);
        bt = bet[col];
      }
#pragma unroll
      for (int j = 0; j < 4; ++j) {
        int row = bn + wr * 32 + fr * 16 + hi16 * 4 + j;
        size_t idx = (size_t)row * m + col;
        float v = acc[fr][fc][j] + bb;
        if (EP == 1) v = siluf(v);
        if (EP == 2) {
          v = (acc[fr][fc][j] + bb) * gs + bt + xres[idx];
          if (extra) v += extra[idx];
        }
        if (EP == 3) {
          if (col < 256) q16[(size_t)row * 768 + col] = f2bf(v * 0.25500526764f);
          else if (col < 512) q16[(size_t)row * 768 + col] = f2bf(v);
          else Vt[(size_t)(col - 512) * 4096 + row] = f2bf(v);
        } else {
          C[idx] = v;
        }
      }
    }
}

// ---------------- LayerNorm -> bf16 ----------------

__global__ __launch_bounds__(256) void layernorm16_k(const float* __restrict__ x,
    const float* __restrict__ g, const float* __restrict__ b, u16* __restrict__ xn) {
  int row = blockIdx.x, t = threadIdx.x;
  float v = x[(size_t)row * DD + t];
  float s = v, sq = v * v;
#pragma unroll
  for (int o = 32; o > 0; o >>= 1) { s += __shfl_down(s, o); sq += __shfl_down(sq, o); }
  __shared__ float rs[4], rq[4];
  int wid = t >> 6, lane = t & 63;
  if (lane == 0) { rs[wid] = s; rq[wid] = sq; }
  __syncthreads();
  float S = rs[0] + rs[1] + rs[2] + rs[3];
  float SQ = rq[0] + rq[1] + rq[2] + rq[3];
  float mu = S * (1.f / 256.f);
  float var = SQ * (1.f / 256.f) - mu * mu;
  float inv = rsqrtf(var + 1e-5f);
  xn[(size_t)row * DD + t] = f2bf((v - mu) * inv * g[t] + b[t]);
}

// ---------------- MFMA flash attention, XCD-swizzled (h = blockIdx & 7) ----------------

__global__ __launch_bounds__(256) void flash3(const u16* __restrict__ qkv16,
                                              const u16* __restrict__ Vt,
                                              float* __restrict__ attno) {
  const int bid = blockIdx.x;
  const int h = bid & 7, qb = bid >> 3;   // same-head blocks land on same XCD
  const int tid = threadIdx.x, wid = tid >> 6;
  const int l15 = tid & 15, hi = (tid >> 4) & 3;
  __shared__ u16 Pf[4][2][64][8];

  const bf8 qf = *(const bf8*)(qkv16 +
      (size_t)(qb * 64 + wid * 16 + l15) * 768 + h * 32 + hi * 8);

  float m = -3.0e38f, l = 0.f;
  f32x4 oa0 = {}, oa1 = {};

  for (int t = 0; t < NN; t += 64) {
    f32x4 sc[4];
    const u16* kbase = qkv16 + (size_t)t * 768 + 256 + h * 32 + hi * 8;
#pragma unroll
    for (int f = 0; f < 4; ++f) {
      bf8 kf = *(const bf8*)(kbase + (size_t)(f * 16 + l15) * 768);
      f32x4 z = {};
      sc[f] = __builtin_amdgcn_mfma_f32_16x16x32_bf16(kf, qf, z, 0, 0, 0);
    }
    bf8 vf[2][2];
    const u16* vtb = Vt + (size_t)(h * 32) * 4096 + t;
#pragma unroll
    for (int s = 0; s < 2; ++s)
#pragma unroll
      for (int a = 0; a < 2; ++a)
        vf[s][a] = *(const bf8*)(vtb + (size_t)(a * 16 + l15) * 4096 + s * 32 + hi * 8);
    float mx = sc[0][0];
#pragma unroll
    for (int f = 0; f < 4; ++f)
#pragma unroll
      for (int j = 0; j < 4; ++j) mx = fmaxf(mx, sc[f][j]);
    mx = fmaxf(mx, __shfl_xor(mx, 16));
    mx = fmaxf(mx, __shfl_xor(mx, 32));
    float mn = fmaxf(m, mx);
    float scale = exp2f(m - mn);
    m = mn;
    float sum = 0.f;
#pragma unroll
    for (int f = 0; f < 4; ++f)
#pragma unroll
      for (int j = 0; j < 4; ++j) { sc[f][j] = exp2f(sc[f][j] - mn); sum += sc[f][j]; }
    sum += __shfl_xor(sum, 16);
    sum += __shfl_xor(sum, 32);
    l = l * scale + sum;
#pragma unroll
    for (int j = 0; j < 4; ++j) {
      float scj = __shfl(scale, hi * 4 + j);
      oa0[j] *= scj; oa1[j] *= scj;
    }
#pragma unroll
    for (int f = 0; f < 4; ++f) {
      unsigned lo, hi2;
      asm("v_cvt_pk_bf16_f32 %0, %1, %2" : "=v"(lo) : "v"(sc[f][0]), "v"(sc[f][1]));
      asm("v_cvt_pk_bf16_f32 %0, %1, %2" : "=v"(hi2) : "v"(sc[f][2]), "v"(sc[f][3]));
      uint2 pr; pr.x = lo; pr.y = hi2;
      *(uint2*)&Pf[wid][f >> 1][l15 | (((f * 2 + (hi >> 1)) & 3) << 4)][(hi & 1) * 4] = pr;
    }
#pragma unroll
    for (int s = 0; s < 2; ++s) {
      bf8 pa = *(const bf8*)&Pf[wid][s][l15 | (hi << 4)][0];
      oa0 = __builtin_amdgcn_mfma_f32_16x16x32_bf16(pa, vf[s][0], oa0, 0, 0, 0);
      oa1 = __builtin_amdgcn_mfma_f32_16x16x32_bf16(pa, vf[s][1], oa1, 0, 0, 0);
    }
  }
#pragma unroll
  for (int j = 0; j < 4; ++j) {
    float lj = __shfl(l, hi * 4 + j);
    float inv = 1.f / lj;
    int q = qb * 64 + wid * 16 + hi * 4 + j;
    attno[(size_t)q * DD + h * 32 + l15] = oa0[j] * inv;
    attno[(size_t)q * DD + h * 32 + 16 + l15] = oa1[j] * inv;
  }
}

// ---------------- KAN: cat = [silu(h) | 7 spline bases] bf16 [N][2048] ----------------

__global__ __launch_bounds__(256) void bsplcat_k(const float* __restrict__ h,
                                                 u16* __restrict__ cat) {
  int i = blockIdx.x * 256 + threadIdx.x;  // < N*D
  float v = h[i];
  int row = i >> 8, col = i & 255;
  u16* crow = cat + (size_t)row * 2048;
  crow[col] = f2bf(siluf(v));
  float b[10];
#pragma unroll
  for (int j = 0; j < 10; ++j) {
    float g0 = 0.5f * j - 2.5f;
    b[j] = (v >= g0 && v < g0 + 0.5f) ? 1.f : 0.f;
  }
#pragma unroll
  for (int kk = 1; kk <= 3; ++kk) {
    float inv = 2.f / (float)kk;
#pragma unroll
    for (int j = 0; j + kk < 10; ++j) {
      float g0 = 0.5f * j - 2.5f;
      float g1 = 0.5f * (j + kk + 1) - 2.5f;
      b[j] = (v - g0) * inv * b[j] + (g1 - v) * inv * b[j + 1];
    }
  }
  u16* o = crow + 256 + col * 7;
#pragma unroll
  for (int c = 0; c < 7; ++c) o[c] = f2bf(b[c]);
}

// ---------------- launcher ----------------

extern "C" void kernel_launch(void* const* d_in, const int* in_sizes, int n_in,
                              void* d_out, int out_size, void* d_ws, size_t ws_size,
                              hipStream_t stream) {
  const float* x      = (const float*)d_in[0];
  const int* ei       = (const int*)d_in[1];
  const float* gcn_w1 = (const float*)d_in[2];
  const float* gcn_b1 = (const float*)d_in[3];
  const float* gcn_w2 = (const float*)d_in[4];
  const float* gcn_b2 = (const float*)d_in[5];
  const float* ln_g   = (const float*)d_in[6];
  const float* ln_b   = (const float*)d_in[7];
  const float* w_qkv  = (const float*)d_in[8];
  const float* b_qkv  = (const float*)d_in[9];
  const float* w_o    = (const float*)d_in[10];
  const float* b_o    = (const float*)d_in[11];
  const float* a_w1   = (const float*)d_in[12];
  const float* a_b1   = (const float*)d_in[13];
  const float* a_w2   = (const float*)d_in[14];
  const float* a_b2   = (const float*)d_in[15];
  const float* bn1_g  = (const float*)d_in[16];
  const float* bn1_b  = (const float*)d_in[17];
  const float* bn2_g  = (const float*)d_in[18];
  const float* bn2_b  = (const float*)d_in[19];
  const float* k1_base = (const float*)d_in[20];
  const float* k1_spl  = (const float*)d_in[21];
  const float* k1_scl  = (const float*)d_in[22];
  const float* k2_base = (const float*)d_in[23];
  const float* k2_spl  = (const float*)d_in[24];
  const float* k2_scl  = (const float*)d_in[25];

  float* outF = (float*)d_out;

  const size_t ND = (size_t)NN * DD;

  float* ws = (float*)d_ws;
  float* dis    = ws;                          // [NN]
  int*   cnt    = (int*)(dis + NN);            // [NN]
  int*   rowptr = cnt + NN;                    // [NN+1]
  int*   cursor = rowptr + NN + 1;             // [NN]
  int*   esrc   = cursor + NN;                 // [EE]
  float* ew     = (float*)(esrc + EE);         // [EE]
  float* R1 = ew + EE;                  // [ND]   aggr -> attno
  float* R5 = R1 + ND;                  // [2*ND] mid
  float* R4 = R5 + 2 * ND;              // [ND]   xm
  float* R2 = R4 + ND;                  // [ND]   xn16(u16) -> oproj -> h1
  float* R3 = R2 + ND;                  // [4*ND] qkv16+Vt -> cat [N][2048] u16
  float* R6 = R3 + 4 * ND;              // [ND]   hbuf

  float* aggr = R1; float* attno = R1;
  float* mid  = R5;
  float* xm   = R4;
  u16* xn16   = (u16*)R2; float* oproj = R2; float* h1 = R2;
  u16* qkv16  = (u16*)R3;
  u16* Vt     = (u16*)R3 + (size_t)NN * 768;
  u16* cat    = (u16*)R3;
  float* hbuf = R6;

  const dim3 B256(256);
  const float* np = nullptr;
  float* nf = nullptr;
  u16* nu = nullptr;

  // ---- GCN aggregation via CSR gather ----
  (void)hipMemsetAsync(dis, 0, NN * (sizeof(float) + sizeof(int)), stream);
  degcnt_k<<<EE / 256, B256, 0, stream>>>(ei, dis, cnt);
  dis_k<<<NN / 256, B256, 0, stream>>>(dis);
  scan_k<<<1, 1024, 0, stream>>>(cnt, rowptr, cursor);
  fill_k<<<EE / 256, B256, 0, stream>>>(ei, dis, cursor, esrc, ew);
  gather_k<<<NN / 4, B256, 0, stream>>>(x, dis, rowptr, esrc, ew, aggr);
  // ---- GCN MLP + fused BN/residual ----
  mgemm<1, false, false><<<dim3(64, 8), B256, 0, stream>>>(
      aggr, gcn_w1, np, np, gcn_b1, np, np, np, np, mid, nu, nu, NN, HIDN, DD);
  mgemm<2, false, false><<<dim3(64, 4), B256, 0, stream>>>(
      mid, gcn_w2, np, np, gcn_b2, bn1_g, bn1_b, x, np, xm, nu, nu, NN, DD, HIDN);

  // ---- attention branch ----
  layernorm16_k<<<NN, B256, 0, stream>>>(x, ln_g, ln_b, xn16);
  mgemm<3, true, false><<<dim3(64, 12), B256, 0, stream>>>(
      xn16, w_qkv, np, np, b_qkv, np, np, np, np, nf, qkv16, Vt, NN, 768, DD);
  flash3<<<dim3(NN / 64 * HHD), B256, 0, stream>>>(qkv16, Vt, attno);
  mgemm<0, false, false><<<dim3(64, 4), B256, 0, stream>>>(
      attno, w_o, np, np, b_o, np, np, np, np, oproj, nu, nu, NN, DD, DD);
  mgemm<1, false, false><<<dim3(64, 8), B256, 0, stream>>>(
      oproj, a_w1, np, np, a_b1, np, np, np, np, mid, nu, nu, NN, HIDN, DD);
  mgemm<2, false, false><<<dim3(64, 4), B256, 0, stream>>>(
      mid, a_w2, np, np, a_b2, bn2_g, bn2_b, x, xm, hbuf, nu, nu, NN, DD, HIDN);

  // ---- KAN layer 1 ----
  bsplcat_k<<<ND / 256, B256, 0, stream>>>(hbuf, cat);
  mgemm<0, true, true><<<dim3(64, 4), B256, 0, stream>>>(
      cat, k1_base, k1_spl, k1_scl, np, np, np, np, np, h1, nu, nu, NN, DD, 2048);
  // ---- KAN layer 2 ----
  bsplcat_k<<<ND / 256, B256, 0, stream>>>(h1, cat);
  mgemm<0, true, true><<<dim3(64, 4), B256, 0, stream>>>(
      cat, k2_base, k2_spl, k2_scl, np, np, np, np, np, outF, nu, nu, NN, DD, 2048);
}